// Round 5
// baseline (486.351 us; speedup 1.0000x reference)
//
#include <hip/hip_runtime.h>
#include <hip/hip_bf16.h>

#define HIDDEN 1024
#define FFN    2816
#define NEXP   8
#define NTOK   2048

typedef __attribute__((ext_vector_type(8))) short short8;   // 8 bf16 = 4 VGPRs
typedef __attribute__((ext_vector_type(4))) short bf16x4;   // 4 bf16 = 8 B
typedef __attribute__((ext_vector_type(4))) float f32x4;

static __device__ __forceinline__ short f2bf(float f) {
    __hip_bfloat16 h = __float2bfloat16(f);
    return *(short*)&h;
}

// async 16-B global->LDS DMA (lane i lands at ldsbase + i*16)
static __device__ __forceinline__ void gl_lds16(const short* g, short* l) {
    __builtin_amdgcn_global_load_lds(
        (const __attribute__((address_space(1))) void*)g,
        (__attribute__((address_space(3))) void*)l, 16, 0, 0);
}

// counted-vmcnt pipeline primitives (T3/T4): raw barrier, literal waitcnt
#define WAITV(N) asm volatile("s_waitcnt vmcnt(" #N ")" ::: "memory")
#define LGKM0    asm volatile("s_waitcnt lgkmcnt(0)" ::: "memory")
#define BAR()    do { __builtin_amdgcn_s_barrier(); \
                      __builtin_amdgcn_sched_barrier(0); } while (0)

// ---------------- Router body (shared) -----------------------------------------
static __device__ __forceinline__ void
router_body(int t, int lane, const float* __restrict__ x,
            const float* __restrict__ Wgate, int* __restrict__ counts,
            int* __restrict__ tok, float* __restrict__ wts)
{
    float acc[NEXP];
#pragma unroll
    for (int e = 0; e < NEXP; e++) acc[e] = 0.f;
    const float* xrow = x + (size_t)t * HIDDEN;
    for (int h = lane; h < HIDDEN; h += 64) {
        float xv = xrow[h];
#pragma unroll
        for (int e = 0; e < NEXP; e++) acc[e] += xv * Wgate[e * HIDDEN + h];
    }
#pragma unroll
    for (int off = 32; off > 0; off >>= 1) {
#pragma unroll
        for (int e = 0; e < NEXP; e++) acc[e] += __shfl_down(acc[e], off);
    }
    if (lane == 0) {
        float mx = acc[0];
#pragma unroll
        for (int e = 1; e < NEXP; e++) mx = fmaxf(mx, acc[e]);
        float p[NEXP];
#pragma unroll
        for (int e = 0; e < NEXP; e++) p[e] = __expf(acc[e] - mx);
        int i0 = 0; float p0 = p[0];
#pragma unroll
        for (int e = 1; e < NEXP; e++) if (p[e] > p0) { p0 = p[e]; i0 = e; }
        int i1 = -1; float p1 = -1.f;
#pragma unroll
        for (int e = 0; e < NEXP; e++) {
            if (e == i0) continue;
            if (p[e] > p1) { p1 = p[e]; i1 = e; }
        }
        float inv = 1.f / (p0 + p1);
        float w0 = p0 * inv, w1 = p1 * inv;
        int s0 = atomicAdd(&counts[i0], 1);
        tok[i0 * NTOK + s0] = t; wts[i0 * NTOK + s0] = w0;
        int s1 = atomicAdd(&counts[i1], 1);
        tok[i1 * NTOK + s1] = t; wts[i1 * NTOK + s1] = w1;
    }
}

__global__ void __launch_bounds__(64)
router_kernel(const float* __restrict__ x, const float* __restrict__ Wgate,
              int* __restrict__ counts, int* __restrict__ tok,
              float* __restrict__ wts)
{
    router_body(blockIdx.x, threadIdx.x, x, Wgate, counts, tok, wts);
}

// ---------------- Launch 1: router + x->bf16 + out-zero ------------------------
__global__ void __launch_bounds__(256)
fused_rxz(const float* __restrict__ x, const float* __restrict__ Wgate,
          int* __restrict__ counts, int* __restrict__ tok,
          float* __restrict__ wts, short* __restrict__ xbf,
          float* __restrict__ out)
{
    int bid = blockIdx.x;
    int tid = threadIdx.x;
    if (bid < 512) {
        router_body(bid * 4 + (tid >> 6), tid & 63, x, Wgate, counts, tok, wts);
        return;
    }
    if (bid < 1024) {
        long long base4 = (long long)(bid - 512) * 1024;
#pragma unroll
        for (int p = 0; p < 4; p++) {
            long long r = base4 + p * 256 + tid;
            float4 a = ((const float4*)x)[r];
            bf16x4 o;
            o[0] = f2bf(a.x); o[1] = f2bf(a.y); o[2] = f2bf(a.z); o[3] = f2bf(a.w);
            *(bf16x4*)(xbf + 4 * r) = o;
        }
        return;
    }
    long long base4 = (long long)(bid - 1024) * 1024;
    float4 z = make_float4(0.f, 0.f, 0.f, 0.f);
#pragma unroll
    for (int p = 0; p < 4; p++)
        ((float4*)out)[base4 + p * 256 + tid] = z;
}

// ---------------- Stage A: fp32 weights, 2 reg-sets + 2 LDS bufs (depth-2) -----
// v7 post-mortem: single reg-set gave loads <1 compute phase of flight ->
// latency-bound at 2.1 TB/s effective.  v8: alternating reg sets (A=even tile,
// B=odd tile) + matching LDS buffer parity give EVERY load (reg + DMA) two full
// phases (~>1.2k cyc) of flight.  Steady state: 20 VMEM outstanding/wave;
// WAITV(10) drains exactly the tile about to be consumed.  LDS 48.5 KB ->
// 3 blocks/CU by LDS.  Tail blocks convert Wd (unchanged from v7).
#define FFN1_BLOCKS 2816
#define CVTD_BLOCKS 2048      // NW4 / (11*256)
__global__ void __launch_bounds__(256, 2)
ffn1_v8(const short* __restrict__ xbf, const float* __restrict__ Wg,
        const float* __restrict__ Wu, const int* __restrict__ counts,
        const int* __restrict__ tok, short* __restrict__ hbuf,
        const float* __restrict__ Wd, short* __restrict__ wdbf)
{
    int bid = blockIdx.x;
    int tid = threadIdx.x;
    if (bid >= FFN1_BLOCKS) {
        long long base4 = (long long)(bid - FFN1_BLOCKS) * 2816;
#pragma unroll
        for (int p = 0; p < 11; p++) {
            long long r = base4 + p * 256 + tid;
            float4 a = ((const float4*)Wd)[r];
            bf16x4 o;
            o[0] = f2bf(a.x); o[1] = f2bf(a.y); o[2] = f2bf(a.z); o[3] = f2bf(a.w);
            *(bf16x4*)(wdbf + 4 * r) = o;
        }
        return;
    }
    int xb  = bid / 176;          // SLOWEST (round-3 verified XCD ordering)
    int yz  = bid - xb * 176;
    int e   = yz / 22;
    int fb  = yz - e * 22;
    int cnt = counts[e];
    int row0 = xb * 128;
    if (row0 >= cnt) return;
    int off_e = 0;
#pragma unroll
    for (int i = 0; i < NEXP; i++) if (i < e) off_e += counts[i];
    int f0 = fb * 128;

    __shared__ short Xs[2][128 * 32];
    __shared__ short Gs[2][128 * 32];
    __shared__ short Us[2][128 * 32];
    __shared__ int   stok[128];

    if (tid < 128) stok[tid] = tok[e * NTOK + min(row0 + tid, cnt - 1)];
    __syncthreads();

    int lane = tid & 63, w = tid >> 6;
    int l15 = lane & 15, lq = lane >> 4;
    int wm = (w & 1) * 64, wn = (w >> 1) * 64;

    int prow   = lane >> 2;
    int gchunk = (lane & 3) ^ ((lane >> 3) & 3);      // swizzled source chunk
    const short* xsrc[2]; const float* gsrc[2]; const float* usrc[2];
    int rb[2];
#pragma unroll
    for (int j = 0; j < 2; j++) {
        int rbase = w * 32 + j * 16;
        int r = rbase + prow;
        xsrc[j] = xbf + (size_t)stok[r] * HIDDEN + gchunk * 8;
        gsrc[j] = Wg + (size_t)e * FFN * HIDDEN + (size_t)(f0 + r) * HIDDEN + gchunk * 8;
        usrc[j] = Wu + (size_t)e * FFN * HIDDEN + (size_t)(f0 + r) * HIDDEN + gchunk * 8;
        rb[j] = rbase * 32;
    }
    int wadr0 = rb[0] + lane * 8;   // shorts; == DMA landing slot (lane*16 B)
    int wadr1 = rb[1] + lane * 8;

    int aoff[4], boff[4];
#pragma unroll
    for (int mi = 0; mi < 4; mi++) {
        int r = wm + mi * 16 + l15;
        aoff[mi] = r * 32 + (lq ^ ((r >> 1) & 3)) * 8;
    }
#pragma unroll
    for (int ni = 0; ni < 4; ni++) {
        int r = wn + ni * 16 + l15;
        boff[ni] = r * 32 + (lq ^ ((r >> 1) & 3)) * 8;
    }

    f32x4 cg[4][4], cu[4][4];
#pragma unroll
    for (int i = 0; i < 4; i++)
#pragma unroll
        for (int j = 0; j < 4; j++) { cg[i][j] = (f32x4)0.f; cu[i][j] = (f32x4)0.f; }

    // two independent staging reg sets (named vars: rule #20, static indexing)
    float4 Ag0a, Ag0b, Ag1a, Ag1b, Au0a, Au0b, Au1a, Au1b;
    float4 Bg0a, Bg0b, Bg1a, Bg1b, Bu0a, Bu0b, Bu1a, Bu1b;

#define XDMA(B, T) do { int _k = (T) * 32;                          \
    gl_lds16(xsrc[0] + _k, &Xs[B][rb[0]]);                          \
    gl_lds16(xsrc[1] + _k, &Xs[B][rb[1]]); } while (0)

#define LOADR_A(T) do { int _k = (T) * 32;                          \
    Ag0a = *(const float4*)(gsrc[0] + _k);                          \
    Ag0b = *(const float4*)(gsrc[0] + _k + 4);                      \
    Ag1a = *(const float4*)(gsrc[1] + _k);                          \
    Ag1b = *(const float4*)(gsrc[1] + _k + 4);                      \
    Au0a = *(const float4*)(usrc[0] + _k);                          \
    Au0b = *(const float4*)(usrc[0] + _k + 4);                      \
    Au1a = *(const float4*)(usrc[1] + _k);                          \
    Au1b = *(const float4*)(usrc[1] + _k + 4); } while (0)

#define LOADR_B(T) do { int _k = (T) * 32;                          \
    Bg0a = *(const float4*)(gsrc[0] + _k);                          \
    Bg0b = *(const float4*)(gsrc[0] + _k + 4);                      \
    Bg1a = *(const float4*)(gsrc[1] + _k);                          \
    Bg1b = *(const float4*)(gsrc[1] + _k + 4);                      \
    Bu0a = *(const float4*)(usrc[0] + _k);                          \
    Bu0b = *(const float4*)(usrc[0] + _k + 4);                      \
    Bu1a = *(const float4*)(usrc[1] + _k);                          \
    Bu1b = *(const float4*)(usrc[1] + _k + 4); } while (0)

#define PK8(dst, A, Bv) do { short8 _o;                             \
    _o[0] = f2bf(A.x);  _o[1] = f2bf(A.y);                          \
    _o[2] = f2bf(A.z);  _o[3] = f2bf(A.w);                          \
    _o[4] = f2bf(Bv.x); _o[5] = f2bf(Bv.y);                         \
    _o[6] = f2bf(Bv.z); _o[7] = f2bf(Bv.w);                         \
    *(short8*)(dst) = _o; } while (0)

#define CVTW_A() do {                                               \
    PK8(&Gs[0][wadr0], Ag0a, Ag0b); PK8(&Gs[0][wadr1], Ag1a, Ag1b); \
    PK8(&Us[0][wadr0], Au0a, Au0b); PK8(&Us[0][wadr1], Au1a, Au1b); } while (0)

#define CVTW_B() do {                                               \
    PK8(&Gs[1][wadr0], Bg0a, Bg0b); PK8(&Gs[1][wadr1], Bg1a, Bg1b); \
    PK8(&Us[1][wadr0], Bu0a, Bu0b); PK8(&Us[1][wadr1], Bu1a, Bu1b); } while (0)

#define COMP1(B) do {                                               \
    short8 af[4];                                                   \
    _Pragma("unroll")                                               \
    for (int mi = 0; mi < 4; mi++)                                  \
        af[mi] = *(const short8*)&Xs[B][aoff[mi]];                  \
    {   short8 bb[4];                                               \
        _Pragma("unroll")                                           \
        for (int ni = 0; ni < 4; ni++)                              \
            bb[ni] = *(const short8*)&Gs[B][boff[ni]];              \
        _Pragma("unroll")                                           \
        for (int mi = 0; mi < 4; mi++)                              \
        _Pragma("unroll")                                           \
        for (int ni = 0; ni < 4; ni++)                              \
            cg[mi][ni] = __builtin_amdgcn_mfma_f32_16x16x32_bf16(af[mi], bb[ni], cg[mi][ni], 0, 0, 0); \
    }                                                               \
    {   short8 bb[4];                                               \
        _Pragma("unroll")                                           \
        for (int ni = 0; ni < 4; ni++)                              \
            bb[ni] = *(const short8*)&Us[B][boff[ni]];              \
        _Pragma("unroll")                                           \
        for (int mi = 0; mi < 4; mi++)                              \
        _Pragma("unroll")                                           \
        for (int ni = 0; ni < 4; ni++)                              \
            cu[mi][ni] = __builtin_amdgcn_mfma_f32_16x16x32_bf16(af[mi], bb[ni], cu[mi][ni], 0, 0, 0); \
    } } while (0)

    // prologue: tiles 0 (set A, buf0) and 1 (set B, buf1) in flight = 20 VMEM
    LOADR_A(0); XDMA(0, 0);
    LOADR_B(1); XDMA(1, 1);

    // Invariants (traced): at loop top, outstanding = tile tt (10, oldest) +
    // tile tt+1 (10).  WAITV(10) drains tile tt.  Mid-loop after issuing
    // tile tt+2: outstanding = tt+1 (oldest) + tt+2 -> WAITV(10) drains tt+1.
    // Tail (tt=30): no reissue -> WAITV(0) drains tile 31.
    for (int tt = 0; tt < 32; tt += 2) {
        WAITV(10);
        CVTW_A(); LGKM0; BAR();
        COMP1(0);
        BAR();
        if (tt + 2 < 32) { LOADR_A(tt + 2); XDMA(0, tt + 2); WAITV(10); }
        else             { WAITV(0); }
        CVTW_B(); LGKM0; BAR();
        COMP1(1);
        BAR();
        if (tt + 3 < 32) { LOADR_B(tt + 3); XDMA(1, tt + 3); }
    }

#undef XDMA
#undef LOADR_A
#undef LOADR_B
#undef PK8
#undef CVTW_A
#undef CVTW_B
#undef COMP1

    // epilogue: silu(g)*u -> bf16 hbuf.  C/D: col=lane&15, row=lq*4+reg
#pragma unroll
    for (int mi = 0; mi < 4; mi++)
#pragma unroll
        for (int r = 0; r < 4; r++) {
            int row = wm + mi * 16 + lq * 4 + r;
            int grow = row0 + row;
            if (grow < cnt) {
                short* hrow = hbuf + (size_t)(off_e + grow) * FFN + f0 + wn;
#pragma unroll
                for (int ni = 0; ni < 4; ni++) {
                    float g = cg[mi][ni][r], u = cu[mi][ni][r];
                    float h = g / (1.f + __expf(-g)) * u;
                    hrow[ni * 16 + l15] = f2bf(h);
                }
            }
        }
}

// ---------------- Stage B: 128x128 tile, K split in 2 (UNCHANGED) --------------
__global__ void __launch_bounds__(256, 2)
ffn2_v6(const short* __restrict__ hbuf, const short* __restrict__ Wdbf,
        const int* __restrict__ counts, const int* __restrict__ tok,
        const float* __restrict__ wts, float* __restrict__ out)
{
    int bid = blockIdx.x;
    int xb  = bid >> 7;
    int yz  = bid & 127;
    int e   = yz >> 4;
    int y   = yz & 15;
    int cnt = counts[e];
    int row0 = xb * 128;
    if (row0 >= cnt) return;
    int off_e = 0;
#pragma unroll
    for (int i = 0; i < NEXP; i++) if (i < e) off_e += counts[i];
    int h0    = (y >> 1) * 128;
    int kbase = (y & 1) * (FFN / 2);

    __shared__ short Hs[3][128 * 32];
    __shared__ short Ds[3][128 * 32];
    __shared__ int   stok[128];
    __shared__ float swt[128];

    int tid = threadIdx.x;
    if (tid < 128) {
        int rc = min(row0 + tid, cnt - 1);
        stok[tid] = tok[e * NTOK + rc];
        swt[tid]  = wts[e * NTOK + rc];
    }
    __syncthreads();

    int lane = tid & 63, w = tid >> 6;
    int l15 = lane & 15, lq = lane >> 4;
    int wm = (w & 1) * 64, wn = (w >> 1) * 64;

    int prow   = lane >> 2;
    int gchunk = (lane & 3) ^ ((lane >> 3) & 3);
    const short* hsrc[2]; const short* dsrc[2];
    int rb[2];
#pragma unroll
    for (int j = 0; j < 2; j++) {
        int rbase = w * 32 + j * 16;
        int r = rbase + prow;
        hsrc[j] = hbuf + (size_t)(off_e + min(row0 + r, cnt - 1)) * FFN + kbase + gchunk * 8;
        dsrc[j] = Wdbf + (size_t)e * HIDDEN * FFN + (size_t)(h0 + r) * FFN + kbase + gchunk * 8;
        rb[j] = rbase * 32;
    }

    int aoff[4], boff[4];
#pragma unroll
    for (int mi = 0; mi < 4; mi++) {
        int r = wm + mi * 16 + l15;
        aoff[mi] = r * 32 + (lq ^ ((r >> 1) & 3)) * 8;
    }
#pragma unroll
    for (int ni = 0; ni < 4; ni++) {
        int r = wn + ni * 16 + l15;
        boff[ni] = r * 32 + (lq ^ ((r >> 1) & 3)) * 8;
    }

    f32x4 c[4][4];
#pragma unroll
    for (int i = 0; i < 4; i++)
#pragma unroll
        for (int j = 0; j < 4; j++) c[i][j] = (f32x4)0.f;

#define STAGE2(B, T) do { int _k = (T) * 32;                       \
    _Pragma("unroll")                                              \
    for (int j = 0; j < 2; j++) {                                  \
        gl_lds16(hsrc[j] + _k, &Hs[B][rb[j]]);                     \
        gl_lds16(dsrc[j] + _k, &Ds[B][rb[j]]);                     \
    } } while (0)

#define COMP2(B) do {                                              \
    short8 af[4], bd[4];                                           \
    _Pragma("unroll")                                              \
    for (int mi = 0; mi < 4; mi++)                                 \
        af[mi] = *(const short8*)&Hs[B][aoff[mi]];                 \
    _Pragma("unroll")                                              \
    for (int ni = 0; ni < 4; ni++)                                 \
        bd[ni] = *(const short8*)&Ds[B][boff[ni]];                 \
    _Pragma("unroll")                                              \
    for (int mi = 0; mi < 4; mi++)                                 \
    _Pragma("unroll")                                              \
    for (int ni = 0; ni < 4; ni++)                                 \
        c[mi][ni] = __builtin_amdgcn_mfma_f32_16x16x32_bf16(af[mi], bd[ni], c[mi][ni], 0, 0, 0); \
    } while (0)

    STAGE2(0, 0); STAGE2(1, 1); STAGE2(2, 2);

    for (int tt = 0; tt < 42; tt += 3) {
        WAITV(8); BAR(); COMP2(0); BAR(); STAGE2(0, tt + 3);
        WAITV(8); BAR(); COMP2(1); BAR(); STAGE2(1, tt + 4);
        WAITV(8); BAR(); COMP2(2); BAR(); if (tt + 5 < 44) STAGE2(2, tt + 5);
    }
    WAITV(4); BAR(); COMP2(0);
    WAITV(0); BAR(); COMP2(1);

#undef STAGE2
#undef COMP2

#pragma unroll
    for (int mi = 0; mi < 4; mi++)
#pragma unroll
        for (int r = 0; r < 4; r++) {
            int row = wm + mi * 16 + lq * 4 + r;
            int grow = row0 + row;
            if (grow < cnt) {
                int t = stok[row];
                float wgt = swt[row];
                float* orow = out + (size_t)t * HIDDEN + h0 + wn;
#pragma unroll
                for (int ni = 0; ni < 4; ni++)
                    atomicAdd(&orow[ni * 16 + l15], wgt * c[mi][ni][r]);
            }
        }
}

// ================= Fallback path (R2 kernels, used if ws too small) ============
#define LDW 40
__global__ void __launch_bounds__(256, 2)
ffn1_fb(const float* __restrict__ x, const float* __restrict__ Wg,
        const float* __restrict__ Wu, const int* __restrict__ counts,
        const int* __restrict__ tok, __hip_bfloat16* __restrict__ hbuf)
{
    int e = blockIdx.z;
    int cnt = counts[e];
    int row0 = blockIdx.x * 128;
    if (row0 >= cnt) return;
    int off_e = 0;
#pragma unroll
    for (int i = 0; i < NEXP; i++) if (i < e) off_e += counts[i];
    int f0 = blockIdx.y * 64;

    __shared__ short Xs[128][LDW];
    __shared__ short Gs[64][LDW];
    __shared__ short Us[64][LDW];
    __shared__ int   stok[128];

    int tid = threadIdx.x;
    if (tid < 128) stok[tid] = tok[e * NTOK + min(row0 + tid, cnt - 1)];
    __syncthreads();

    int lane = tid & 63, w = tid >> 6;
    int wm = (w & 1) * 64, wn = (w >> 1) * 32;
    int l15 = lane & 15, lq = lane >> 4;

    f32x4 cg[4][2], cu[4][2];
#pragma unroll
    for (int i = 0; i < 4; i++)
#pragma unroll
        for (int j = 0; j < 2; j++) { cg[i][j] = (f32x4)0.f; cu[i][j] = (f32x4)0.f; }

    const float* Wge = Wg + (size_t)e * FFN * HIDDEN;
    const float* Wue = Wu + (size_t)e * FFN * HIDDEN;

    int xr[4], xc[4]; const float* xp[4];
#pragma unroll
    for (int i = 0; i < 4; i++) {
        int idx = tid + 256 * i;
        xr[i] = idx >> 3; xc[i] = (idx & 7) * 4;
        xp[i] = x + (size_t)stok[xr[i]] * HIDDEN + xc[i];
    }
    int wr[2], wc[2]; const float* gp[2]; const float* up[2];
#pragma unroll
    for (int i = 0; i < 2; i++) {
        int idx = tid + 256 * i;
        wr[i] = idx >> 3; wc[i] = (idx & 7) * 4;
        gp[i] = Wge + (size_t)(f0 + wr[i]) * HIDDEN + wc[i];
        up[i] = Wue + (size_t)(f0 + wr[i]) * HIDDEN + wc[i];
    }

    float4 xa[4], ga[2], ua[2];
#pragma unroll
    for (int i = 0; i < 4; i++) xa[i] = *(const float4*)(xp[i]);
#pragma unroll
    for (int i = 0; i < 2; i++) { ga[i] = *(const float4*)(gp[i]); ua[i] = *(const float4*)(up[i]); }

    for (int k0 = 0; k0 < HIDDEN; k0 += 32) {
        __syncthreads();
#pragma unroll
        for (int i = 0; i < 4; i++) {
            short* d = &Xs[xr[i]][xc[i]];
            d[0] = f2bf(xa[i].x); d[1] = f2bf(xa[i].y);
            d[2] = f2bf(xa[i].z); d[3] = f2bf(xa[i].w);
        }
#pragma unroll
        for (int i = 0; i < 2; i++) {
            short* d = &Gs[wr[i]][wc[i]];
            d[0] = f2bf(ga[i].x); d[1] = f2bf(ga[i].y);
            d[2] = f2bf(ga[i].z); d[3] = f2bf(ga[i].w);
            short* d2 = &Us[wr[i]][wc[i]];
            d2[0] = f2bf(ua[i].x); d2[1] = f2bf(ua[i].y);
            d2[2] = f2bf(ua[i].z); d2[3] = f2bf(ua[i].w);
        }
        __syncthreads();
        if (k0 + 32 < HIDDEN) {
            int kn = k0 + 32;
#pragma unroll
            for (int i = 0; i < 4; i++) xa[i] = *(const float4*)(xp[i] + kn);
#pragma unroll
            for (int i = 0; i < 2; i++) { ga[i] = *(const float4*)(gp[i] + kn); ua[i] = *(const float4*)(up[i] + kn); }
        }
        short8 af[4], bg[2], bu[2];
#pragma unroll
        for (int mi = 0; mi < 4; mi++) af[mi] = *(const short8*)&Xs[wm + mi * 16 + l15][lq * 8];
#pragma unroll
        for (int ni = 0; ni < 2; ni++) {
            bg[ni] = *(const short8*)&Gs[wn + ni * 16 + l15][lq * 8];
            bu[ni] = *(const short8*)&Us[wn + ni * 16 + l15][lq * 8];
        }
#pragma unroll
        for (int mi = 0; mi < 4; mi++)
#pragma unroll
            for (int ni = 0; ni < 2; ni++) {
                cg[mi][ni] = __builtin_amdgcn_mfma_f32_16x16x32_bf16(af[mi], bg[ni], cg[mi][ni], 0, 0, 0);
                cu[mi][ni] = __builtin_amdgcn_mfma_f32_16x16x32_bf16(af[mi], bu[ni], cu[mi][ni], 0, 0, 0);
            }
    }

#pragma unroll
    for (int mi = 0; mi < 4; mi++)
#pragma unroll
        for (int r = 0; r < 4; r++) {
            int row = wm + mi * 16 + lq * 4 + r;
            int grow = row0 + row;
            if (grow < cnt) {
                __hip_bfloat16* hrow = hbuf + (size_t)(off_e + grow) * FFN + f0 + wn;
#pragma unroll
                for (int ni = 0; ni < 2; ni++) {
                    float g = cg[mi][ni][r], u = cu[mi][ni][r];
                    float h = g / (1.f + __expf(-g)) * u;
                    hrow[ni * 16 + l15] = __float2bfloat16(h);
                }
            }
        }
}

__global__ void __launch_bounds__(256, 2)
ffn2_fb(const __hip_bfloat16* __restrict__ hbuf, const float* __restrict__ Wd,
        const int* __restrict__ counts, const int* __restrict__ tok,
        const float* __restrict__ wts, float* __restrict__ out)
{
    int e = blockIdx.z;
    int cnt = counts[e];
    int row0 = blockIdx.x * 128;
    if (row0 >= cnt) return;
    int off_e = 0;
#pragma unroll
    for (int i = 0; i < NEXP; i++) if (i < e) off_e += counts[i];
    int h0 = blockIdx.y * 64;

    __shared__ short Hs[128][LDW];
    __shared__ short Ds[64][LDW];
    __shared__ int   stok[128];
    __shared__ float swt[128];

    int tid = threadIdx.x;
    if (tid < 128) {
        int rc = min(row0 + tid, cnt - 1);
        stok[tid] = tok[e * NTOK + rc];
        swt[tid]  = wts[e * NTOK + rc];
    }
    __syncthreads();

    int lane = tid & 63, w = tid >> 6;
    int wm = (w & 1) * 64, wn = (w >> 1) * 32;
    int l15 = lane & 15, lq = lane >> 4;

    f32x4 c[4][2];
#pragma unroll
    for (int i = 0; i < 4; i++)
#pragma unroll
        for (int j = 0; j < 2; j++) c[i][j] = (f32x4)0.f;

    const float* Wde = Wd + (size_t)e * HIDDEN * FFN;

    int hr[2], hc[2]; const short* hp[2];
#pragma unroll
    for (int i = 0; i < 2; i++) {
        int idx = tid + 256 * i;
        hr[i] = idx >> 2; hc[i] = (idx & 3) * 8;
        int ar = min(row0 + hr[i], cnt - 1);
        hp[i] = (const short*)(hbuf + (size_t)(off_e + ar) * FFN + hc[i]);
    }
    int dr[2], dc[2]; const float* dp[2];
#pragma unroll
    for (int i = 0; i < 2; i++) {
        int idx = tid + 256 * i;
        dr[i] = idx >> 3; dc[i] = (idx & 7) * 4;
        dp[i] = Wde + (size_t)(h0 + dr[i]) * FFN + dc[i];
    }

    short8 ha[2]; float4 da[2];
#pragma unroll
    for (int i = 0; i < 2; i++) { ha[i] = *(const short8*)(hp[i]); da[i] = *(const float4*)(dp[i]); }

    for (int k0 = 0; k0 < FFN; k0 += 32) {
        __syncthreads();
#pragma unroll
        for (int i = 0; i < 2; i++) {
            *(short8*)&Hs[hr[i]][hc[i]] = ha[i];
            short* d = &Ds[dr[i]][dc[i]];
            d[0] = f2bf(da[i].x); d[1] = f2bf(da[i].y);
            d[2] = f2bf(da[i].z); d[3] = f2bf(da[i].w);
        }
        __syncthreads();
        if (k0 + 32 < FFN) {
            int kn = k0 + 32;
#pragma unroll
            for (int i = 0; i < 2; i++) { ha[i] = *(const short8*)(hp[i] + kn); da[i] = *(const float4*)(dp[i] + kn); }
        }
        short8 af[4], bf_[2];
#pragma unroll
        for (int mi = 0; mi < 4; mi++) af[mi] = *(const short8*)&Hs[wm + mi * 16 + l15][lq * 8];
#pragma unroll
        for (int ni = 0; ni < 2; ni++) bf_[ni] = *(const short8*)&Ds[wn + ni * 16 + l15][lq * 8];
#pragma unroll
        for (int mi = 0; mi < 4; mi++)
#pragma unroll
            for (int ni = 0; ni < 2; ni++)
                c[mi][ni] = __builtin_amdgcn_mfma_f32_16x16x32_bf16(af[mi], bf_[ni], c[mi][ni], 0, 0, 0);
    }

#pragma unroll
    for (int mi = 0; mi < 4; mi++)
#pragma unroll
        for (int r = 0; r < 4; r++) {
            int row = wm + mi * 16 + lq * 4 + r;
            int grow = row0 + row;
            if (grow < cnt) {
                int t = stok[row];
                float wgt = swt[row];
                float* orow = out + (size_t)t * HIDDEN + h0 + wn;
#pragma unroll
                for (int ni = 0; ni < 2; ni++)
                    atomicAdd(&orow[ni * 16 + l15], wgt * c[mi][ni][r]);
            }
        }
}

extern "C" void kernel_launch(void* const* d_in, const int* in_sizes, int n_in,
                              void* d_out, int out_size, void* d_ws, size_t ws_size,
                              hipStream_t stream) {
    const float* x     = (const float*)d_in[0];
    const float* Wgate = (const float*)d_in[1];
    const float* Wg    = (const float*)d_in[2];
    const float* Wu    = (const float*)d_in[3];
    const float* Wd    = (const float*)d_in[4];
    float* out = (float*)d_out;

    char* ws = (char*)d_ws;
    int*   counts = (int*)ws;
    int*   tok    = (int*)(ws + 256);
    float* wts    = (float*)(ws + 256 + NEXP * NTOK * 4);

    hipMemsetAsync(counts, 0, 256, stream);

    const size_t base = 256 + 2 * (size_t)NEXP * NTOK * 4;   // 131328
    const size_t NEED = base
        + 2ull * NTOK * HIDDEN                // xbf
        + 2ull * NEXP * HIDDEN * FFN          // wdbf
        + 2ull * 2ull * NTOK * FFN;           // hbuf (4096 x 2816)

    if (ws_size >= NEED) {
        short* xbf  = (short*)(ws + base);
        short* wdbf = xbf  + (size_t)NTOK * HIDDEN;
        short* hbuf = wdbf + (size_t)NEXP * HIDDEN * FFN;

        // launch 1: router + x->bf16 + out zero-fill (1536 blocks)
        fused_rxz<<<1536, 256, 0, stream>>>(x, Wgate, counts, tok, wts, xbf, out);

        // launch 2: ffn1 (fp32 weights, depth-2 pipeline) + Wd-cvt tail
        ffn1_v8<<<FFN1_BLOCKS + CVTD_BLOCKS, 256, 0, stream>>>(
            xbf, Wg, Wu, counts, tok, hbuf, Wd, wdbf);

        // launch 3: ffn2 (unchanged, bf16 DMA path)
        ffn2_v6<<<2048, 256, 0, stream>>>(hbuf, wdbf, counts, tok, wts, out);
    } else {
        hipMemsetAsync(out, 0, (size_t)out_size * sizeof(float), stream);
        router_kernel<<<NTOK, 64, 0, stream>>>(x, Wgate, counts, tok, wts);
        __hip_bfloat16* hbuf = (__hip_bfloat16*)(ws + base);
        dim3 g1(NTOK / 128, FFN / 64, NEXP);
        ffn1_fb<<<g1, 256, 0, stream>>>(x, Wg, Wu, counts, tok, hbuf);
        dim3 g2(NTOK / 128, HIDDEN / 64, NEXP);
        ffn2_fb<<<g2, 256, 0, stream>>>(hbuf, Wd, counts, tok, wts, out);
    }
}

// Round 6
// 447.048 us; speedup vs baseline: 1.0879x; 1.0879x over previous
//
#include <hip/hip_runtime.h>
#include <hip/hip_bf16.h>

#define HIDDEN 1024
#define FFN    2816
#define NEXP   8
#define NTOK   2048

typedef __attribute__((ext_vector_type(8))) short short8;   // 8 bf16 = 4 VGPRs
typedef __attribute__((ext_vector_type(4))) short bf16x4;   // 4 bf16 = 8 B
typedef __attribute__((ext_vector_type(4))) float f32x4;

static __device__ __forceinline__ short f2bf(float f) {
    __hip_bfloat16 h = __float2bfloat16(f);
    return *(short*)&h;
}

// async 16-B global->LDS DMA (lane i lands at ldsbase + i*16)
static __device__ __forceinline__ void gl_lds16(const short* g, short* l) {
    __builtin_amdgcn_global_load_lds(
        (const __attribute__((address_space(1))) void*)g,
        (__attribute__((address_space(3))) void*)l, 16, 0, 0);
}

// counted-vmcnt pipeline primitives: raw barrier, literal waitcnt
#define WAITV(N) asm volatile("s_waitcnt vmcnt(" #N ")" ::: "memory")
#define LGKM0    asm volatile("s_waitcnt lgkmcnt(0)" ::: "memory")
#define BAR()    do { __builtin_amdgcn_s_barrier(); \
                      __builtin_amdgcn_sched_barrier(0); } while (0)

// ---------------- Router body (shared) -----------------------------------------
static __device__ __forceinline__ void
router_body(int t, int lane, const float* __restrict__ x,
            const float* __restrict__ Wgate, int* __restrict__ counts,
            int* __restrict__ tok, float* __restrict__ wts)
{
    float acc[NEXP];
#pragma unroll
    for (int e = 0; e < NEXP; e++) acc[e] = 0.f;
    const float* xrow = x + (size_t)t * HIDDEN;
    for (int h = lane; h < HIDDEN; h += 64) {
        float xv = xrow[h];
#pragma unroll
        for (int e = 0; e < NEXP; e++) acc[e] += xv * Wgate[e * HIDDEN + h];
    }
#pragma unroll
    for (int off = 32; off > 0; off >>= 1) {
#pragma unroll
        for (int e = 0; e < NEXP; e++) acc[e] += __shfl_down(acc[e], off);
    }
    if (lane == 0) {
        float mx = acc[0];
#pragma unroll
        for (int e = 1; e < NEXP; e++) mx = fmaxf(mx, acc[e]);
        float p[NEXP];
#pragma unroll
        for (int e = 0; e < NEXP; e++) p[e] = __expf(acc[e] - mx);
        int i0 = 0; float p0 = p[0];
#pragma unroll
        for (int e = 1; e < NEXP; e++) if (p[e] > p0) { p0 = p[e]; i0 = e; }
        int i1 = -1; float p1 = -1.f;
#pragma unroll
        for (int e = 0; e < NEXP; e++) {
            if (e == i0) continue;
            if (p[e] > p1) { p1 = p[e]; i1 = e; }
        }
        float inv = 1.f / (p0 + p1);
        float w0 = p0 * inv, w1 = p1 * inv;
        int s0 = atomicAdd(&counts[i0], 1);
        tok[i0 * NTOK + s0] = t; wts[i0 * NTOK + s0] = w0;
        int s1 = atomicAdd(&counts[i1], 1);
        tok[i1 * NTOK + s1] = t; wts[i1 * NTOK + s1] = w1;
    }
}

__global__ void __launch_bounds__(64)
router_kernel(const float* __restrict__ x, const float* __restrict__ Wgate,
              int* __restrict__ counts, int* __restrict__ tok,
              float* __restrict__ wts)
{
    router_body(blockIdx.x, threadIdx.x, x, Wgate, counts, tok, wts);
}

// ---------------- Launch 1: router + x->bf16 + out-zero (unchanged) ------------
__global__ void __launch_bounds__(256)
fused_rxz(const float* __restrict__ x, const float* __restrict__ Wgate,
          int* __restrict__ counts, int* __restrict__ tok,
          float* __restrict__ wts, short* __restrict__ xbf,
          float* __restrict__ out)
{
    int bid = blockIdx.x;
    int tid = threadIdx.x;
    if (bid < 512) {
        router_body(bid * 4 + (tid >> 6), tid & 63, x, Wgate, counts, tok, wts);
        return;
    }
    if (bid < 1024) {
        long long base4 = (long long)(bid - 512) * 1024;
#pragma unroll
        for (int p = 0; p < 4; p++) {
            long long r = base4 + p * 256 + tid;
            float4 a = ((const float4*)x)[r];
            bf16x4 o;
            o[0] = f2bf(a.x); o[1] = f2bf(a.y); o[2] = f2bf(a.z); o[3] = f2bf(a.w);
            *(bf16x4*)(xbf + 4 * r) = o;
        }
        return;
    }
    long long base4 = (long long)(bid - 1024) * 1024;
    float4 z = make_float4(0.f, 0.f, 0.f, 0.f);
#pragma unroll
    for (int p = 0; p < 4; p++)
        ((float4*)out)[base4 + p * 256 + tid] = z;
}

// ---------------- Stage A: exact v7 structure, NO cvt tail ---------------------
// v7 was the best measured ffn1 variant per byte moved (348 MB -> 166 us).
// Removing the Wd-cvt tail blocks drops 138 MB from this dispatch; predicted
// ~100-115 us.  Structure byte-identical to round-4 ffn1_v7 GEMM path.
#define FFN1_BLOCKS 2816
__global__ void __launch_bounds__(256, 2)
ffn1_v10(const short* __restrict__ xbf, const float* __restrict__ Wg,
         const float* __restrict__ Wu, const int* __restrict__ counts,
         const int* __restrict__ tok, short* __restrict__ hbuf)
{
    int bid = blockIdx.x;
    int tid = threadIdx.x;
    int xb  = bid / 176;          // SLOWEST (round-3 verified XCD ordering)
    int yz  = bid - xb * 176;
    int e   = yz / 22;
    int fb  = yz - e * 22;
    int cnt = counts[e];
    int row0 = xb * 128;
    if (row0 >= cnt) return;
    int off_e = 0;
#pragma unroll
    for (int i = 0; i < NEXP; i++) if (i < e) off_e += counts[i];
    int f0 = fb * 128;

    __shared__ short Xs[2][128 * 32];
    __shared__ short Gs[2][128 * 32];
    __shared__ short Us[2][128 * 32];
    __shared__ int   stok[128];

    if (tid < 128) stok[tid] = tok[e * NTOK + min(row0 + tid, cnt - 1)];
    __syncthreads();

    int lane = tid & 63, w = tid >> 6;
    int l15 = lane & 15, lq = lane >> 4;
    int wm = (w & 1) * 64, wn = (w >> 1) * 64;

    int prow   = lane >> 2;
    int gchunk = (lane & 3) ^ ((lane >> 3) & 3);      // swizzled source chunk
    const short* xsrc[2]; const float* gsrc[2]; const float* usrc[2];
    int rb[2];
#pragma unroll
    for (int j = 0; j < 2; j++) {
        int rbase = w * 32 + j * 16;
        int r = rbase + prow;
        xsrc[j] = xbf + (size_t)stok[r] * HIDDEN + gchunk * 8;
        gsrc[j] = Wg + (size_t)e * FFN * HIDDEN + (size_t)(f0 + r) * HIDDEN + gchunk * 8;
        usrc[j] = Wu + (size_t)e * FFN * HIDDEN + (size_t)(f0 + r) * HIDDEN + gchunk * 8;
        rb[j] = rbase * 32;
    }
    int wadr0 = rb[0] + lane * 8;   // shorts; == DMA landing slot (lane*16 B)
    int wadr1 = rb[1] + lane * 8;

    int aoff[4], boff[4];
#pragma unroll
    for (int mi = 0; mi < 4; mi++) {
        int r = wm + mi * 16 + l15;
        aoff[mi] = r * 32 + (lq ^ ((r >> 1) & 3)) * 8;
    }
#pragma unroll
    for (int ni = 0; ni < 4; ni++) {
        int r = wn + ni * 16 + l15;
        boff[ni] = r * 32 + (lq ^ ((r >> 1) & 3)) * 8;
    }

    f32x4 cg[4][4], cu[4][4];
#pragma unroll
    for (int i = 0; i < 4; i++)
#pragma unroll
        for (int j = 0; j < 4; j++) { cg[i][j] = (f32x4)0.f; cu[i][j] = (f32x4)0.f; }

    float4 g0a, g0b, g1a, g1b, u0a, u0b, u1a, u1b;   // single reg set

#define XDMA(B, T) do { int _k = (T) * 32;                          \
    gl_lds16(xsrc[0] + _k, &Xs[B][rb[0]]);                          \
    gl_lds16(xsrc[1] + _k, &Xs[B][rb[1]]); } while (0)

#define LOADR(T) do { int _k = (T) * 32;                            \
    g0a = *(const float4*)(gsrc[0] + _k);                           \
    g0b = *(const float4*)(gsrc[0] + _k + 4);                       \
    g1a = *(const float4*)(gsrc[1] + _k);                           \
    g1b = *(const float4*)(gsrc[1] + _k + 4);                       \
    u0a = *(const float4*)(usrc[0] + _k);                           \
    u0b = *(const float4*)(usrc[0] + _k + 4);                       \
    u1a = *(const float4*)(usrc[1] + _k);                           \
    u1b = *(const float4*)(usrc[1] + _k + 4); } while (0)

#define PK8(dst, A, Bv) do { short8 _o;                             \
    _o[0] = f2bf(A.x);  _o[1] = f2bf(A.y);                          \
    _o[2] = f2bf(A.z);  _o[3] = f2bf(A.w);                          \
    _o[4] = f2bf(Bv.x); _o[5] = f2bf(Bv.y);                         \
    _o[6] = f2bf(Bv.z); _o[7] = f2bf(Bv.w);                         \
    *(short8*)(dst) = _o; } while (0)

#define CVTW(B) do {                                                \
    PK8(&Gs[B][wadr0], g0a, g0b); PK8(&Gs[B][wadr1], g1a, g1b);     \
    PK8(&Us[B][wadr0], u0a, u0b); PK8(&Us[B][wadr1], u1a, u1b); } while (0)

#define COMP1(B) do {                                               \
    short8 af[4];                                                   \
    _Pragma("unroll")                                               \
    for (int mi = 0; mi < 4; mi++)                                  \
        af[mi] = *(const short8*)&Xs[B][aoff[mi]];                  \
    {   short8 bb[4];                                               \
        _Pragma("unroll")                                           \
        for (int ni = 0; ni < 4; ni++)                              \
            bb[ni] = *(const short8*)&Gs[B][boff[ni]];              \
        _Pragma("unroll")                                           \
        for (int mi = 0; mi < 4; mi++)                              \
        _Pragma("unroll")                                           \
        for (int ni = 0; ni < 4; ni++)                              \
            cg[mi][ni] = __builtin_amdgcn_mfma_f32_16x16x32_bf16(af[mi], bb[ni], cg[mi][ni], 0, 0, 0); \
    }                                                               \
    {   short8 bb[4];                                               \
        _Pragma("unroll")                                           \
        for (int ni = 0; ni < 4; ni++)                              \
            bb[ni] = *(const short8*)&Us[B][boff[ni]];              \
        _Pragma("unroll")                                           \
        for (int mi = 0; mi < 4; mi++)                              \
        _Pragma("unroll")                                           \
        for (int ni = 0; ni < 4; ni++)                              \
            cu[mi][ni] = __builtin_amdgcn_mfma_f32_16x16x32_bf16(af[mi], bb[ni], cu[mi][ni], 0, 0, 0); \
    } } while (0)

    XDMA(0, 0); LOADR(0);

    for (int tt = 0; tt < 32; tt += 2) {
        CVTW(0);
        XDMA(1, tt + 1); LOADR(tt + 1);
        WAITV(10); LGKM0; BAR();
        COMP1(0);
        BAR();
        CVTW(1);
        if (tt + 2 < 32) { XDMA(0, tt + 2); LOADR(tt + 2); WAITV(10); }
        else             { WAITV(0); }
        LGKM0; BAR();
        COMP1(1);
        BAR();
    }

#undef XDMA
#undef LOADR
#undef CVTW
#undef COMP1

    // epilogue: silu(g)*u -> bf16 hbuf.  C/D: col=lane&15, row=lq*4+reg
#pragma unroll
    for (int mi = 0; mi < 4; mi++)
#pragma unroll
        for (int r = 0; r < 4; r++) {
            int row = wm + mi * 16 + lq * 4 + r;
            int grow = row0 + row;
            if (grow < cnt) {
                short* hrow = hbuf + (size_t)(off_e + grow) * FFN + f0 + wn;
#pragma unroll
                for (int ni = 0; ni < 4; ni++) {
                    float g = cg[mi][ni][r], u = cu[mi][ni][r];
                    float h = g / (1.f + __expf(-g)) * u;
                    hrow[ni * 16 + l15] = f2bf(h);
                }
            }
        }
}

// ---------------- Stage B: fp32 Wd read directly (reg-staged, v7 pattern) ------
// Eliminates the wdbf round-trip (92 MB fp32 read + 46 wr + 46 rd -> 92 rd).
// Per wave per K-step: 2 H-DMA (bf16 hbuf) + 4 fp32 reg loads = 6 VMEM.
// Same swizzle relations as ffn1 (rbase mult of 16 -> (r>>1)&3 == (lane>>3)&3).
__global__ void __launch_bounds__(256, 2)
ffn2_v9(const short* __restrict__ hbuf, const float* __restrict__ Wd,
        const int* __restrict__ counts, const int* __restrict__ tok,
        const float* __restrict__ wts, float* __restrict__ out)
{
    int bid = blockIdx.x;
    int xb  = bid >> 7;           // SLOWEST
    int yz  = bid & 127;
    int e   = yz >> 4;
    int y   = yz & 15;
    int cnt = counts[e];
    int row0 = xb * 128;
    if (row0 >= cnt) return;
    int off_e = 0;
#pragma unroll
    for (int i = 0; i < NEXP; i++) if (i < e) off_e += counts[i];
    int h0    = (y >> 1) * 128;
    int kbase = (y & 1) * (FFN / 2);

    __shared__ short Hs[2][128 * 32];
    __shared__ short Ds[2][128 * 32];
    __shared__ int   stok[128];
    __shared__ float swt[128];

    int tid = threadIdx.x;
    if (tid < 128) {
        int rc = min(row0 + tid, cnt - 1);
        stok[tid] = tok[e * NTOK + rc];
        swt[tid]  = wts[e * NTOK + rc];
    }
    __syncthreads();

    int lane = tid & 63, w = tid >> 6;
    int l15 = lane & 15, lq = lane >> 4;
    int wm = (w & 1) * 64, wn = (w >> 1) * 64;

    int prow   = lane >> 2;
    int gchunk = (lane & 3) ^ ((lane >> 3) & 3);
    const short* hsrc[2]; const float* dsrc[2];
    int rb[2];
#pragma unroll
    for (int j = 0; j < 2; j++) {
        int rbase = w * 32 + j * 16;
        int r = rbase + prow;
        hsrc[j] = hbuf + (size_t)(off_e + min(row0 + r, cnt - 1)) * FFN + kbase + gchunk * 8;
        dsrc[j] = Wd + (size_t)e * HIDDEN * FFN + (size_t)(h0 + r) * FFN + kbase + gchunk * 8;
        rb[j] = rbase * 32;
    }
    int wadr0 = rb[0] + lane * 8;
    int wadr1 = rb[1] + lane * 8;

    int aoff[4], boff[4];
#pragma unroll
    for (int mi = 0; mi < 4; mi++) {
        int r = wm + mi * 16 + l15;
        aoff[mi] = r * 32 + (lq ^ ((r >> 1) & 3)) * 8;
    }
#pragma unroll
    for (int ni = 0; ni < 4; ni++) {
        int r = wn + ni * 16 + l15;
        boff[ni] = r * 32 + (lq ^ ((r >> 1) & 3)) * 8;
    }

    f32x4 c[4][4];
#pragma unroll
    for (int i = 0; i < 4; i++)
#pragma unroll
        for (int j = 0; j < 4; j++) c[i][j] = (f32x4)0.f;

    float4 d0a, d0b, d1a, d1b;   // single reg set for Wd staging

#define HDMA(B, T) do { int _k = (T) * 32;                          \
    gl_lds16(hsrc[0] + _k, &Hs[B][rb[0]]);                          \
    gl_lds16(hsrc[1] + _k, &Hs[B][rb[1]]); } while (0)

#define LOADD(T) do { int _k = (T) * 32;                            \
    d0a = *(const float4*)(dsrc[0] + _k);                           \
    d0b = *(const float4*)(dsrc[0] + _k + 4);                       \
    d1a = *(const float4*)(dsrc[1] + _k);                           \
    d1b = *(const float4*)(dsrc[1] + _k + 4); } while (0)

#define CVTD(B) do {                                                \
    PK8(&Ds[B][wadr0], d0a, d0b); PK8(&Ds[B][wadr1], d1a, d1b); } while (0)

#define COMP2(B) do {                                               \
    short8 af[4], bd[4];                                            \
    _Pragma("unroll")                                               \
    for (int mi = 0; mi < 4; mi++)                                  \
        af[mi] = *(const short8*)&Hs[B][aoff[mi]];                  \
    _Pragma("unroll")                                               \
    for (int ni = 0; ni < 4; ni++)                                  \
        bd[ni] = *(const short8*)&Ds[B][boff[ni]];                  \
    _Pragma("unroll")                                               \
    for (int mi = 0; mi < 4; mi++)                                  \
    _Pragma("unroll")                                               \
    for (int ni = 0; ni < 4; ni++)                                  \
        c[mi][ni] = __builtin_amdgcn_mfma_f32_16x16x32_bf16(af[mi], bd[ni], c[mi][ni], 0, 0, 0); \
    } while (0)

    // NT = (FFN/2)/32 = 44 tiles, unrolled x2 for static buffer parity.
    HDMA(0, 0); LOADD(0);

    for (int tt = 0; tt < 44; tt += 2) {
        CVTD(0);                              // auto-waits tile tt's reg loads
        HDMA(1, tt + 1); LOADD(tt + 1);
        WAITV(6); LGKM0; BAR();               // own H-DMA(tt) drained pre-barrier
        COMP2(0);
        BAR();
        CVTD(1);
        if (tt + 2 < 44) { HDMA(0, tt + 2); LOADD(tt + 2); WAITV(6); }
        else             { WAITV(0); }
        LGKM0; BAR();
        COMP2(1);
        BAR();
    }

#undef HDMA
#undef LOADD
#undef CVTD
#undef COMP2
#undef PK8

#pragma unroll
    for (int mi = 0; mi < 4; mi++)
#pragma unroll
        for (int r = 0; r < 4; r++) {
            int row = wm + mi * 16 + lq * 4 + r;
            int grow = row0 + row;
            if (grow < cnt) {
                int t = stok[row];
                float wgt = swt[row];
                float* orow = out + (size_t)t * HIDDEN + h0 + wn;
#pragma unroll
                for (int ni = 0; ni < 4; ni++)
                    atomicAdd(&orow[ni * 16 + l15], wgt * c[mi][ni][r]);
            }
        }
}

// ================= Fallback path (R2 kernels, used if ws too small) ============
#define LDW 40
__global__ void __launch_bounds__(256, 2)
ffn1_fb(const float* __restrict__ x, const float* __restrict__ Wg,
        const float* __restrict__ Wu, const int* __restrict__ counts,
        const int* __restrict__ tok, __hip_bfloat16* __restrict__ hbuf)
{
    int e = blockIdx.z;
    int cnt = counts[e];
    int row0 = blockIdx.x * 128;
    if (row0 >= cnt) return;
    int off_e = 0;
#pragma unroll
    for (int i = 0; i < NEXP; i++) if (i < e) off_e += counts[i];
    int f0 = blockIdx.y * 64;

    __shared__ short Xs[128][LDW];
    __shared__ short Gs[64][LDW];
    __shared__ short Us[64][LDW];
    __shared__ int   stok[128];

    int tid = threadIdx.x;
    if (tid < 128) stok[tid] = tok[e * NTOK + min(row0 + tid, cnt - 1)];
    __syncthreads();

    int lane = tid & 63, w = tid >> 6;
    int wm = (w & 1) * 64, wn = (w >> 1) * 32;
    int l15 = lane & 15, lq = lane >> 4;

    f32x4 cg[4][2], cu[4][2];
#pragma unroll
    for (int i = 0; i < 4; i++)
#pragma unroll
        for (int j = 0; j < 2; j++) { cg[i][j] = (f32x4)0.f; cu[i][j] = (f32x4)0.f; }

    const float* Wge = Wg + (size_t)e * FFN * HIDDEN;
    const float* Wue = Wu + (size_t)e * FFN * HIDDEN;

    int xr[4], xc[4]; const float* xp[4];
#pragma unroll
    for (int i = 0; i < 4; i++) {
        int idx = tid + 256 * i;
        xr[i] = idx >> 3; xc[i] = (idx & 7) * 4;
        xp[i] = x + (size_t)stok[xr[i]] * HIDDEN + xc[i];
    }
    int wr[2], wc[2]; const float* gp[2]; const float* up[2];
#pragma unroll
    for (int i = 0; i < 2; i++) {
        int idx = tid + 256 * i;
        wr[i] = idx >> 3; wc[i] = (idx & 7) * 4;
        gp[i] = Wge + (size_t)(f0 + wr[i]) * HIDDEN + wc[i];
        up[i] = Wue + (size_t)(f0 + wr[i]) * HIDDEN + wc[i];
    }

    float4 xa[4], ga[2], ua[2];
#pragma unroll
    for (int i = 0; i < 4; i++) xa[i] = *(const float4*)(xp[i]);
#pragma unroll
    for (int i = 0; i < 2; i++) { ga[i] = *(const float4*)(gp[i]); ua[i] = *(const float4*)(up[i]); }

    for (int k0 = 0; k0 < HIDDEN; k0 += 32) {
        __syncthreads();
#pragma unroll
        for (int i = 0; i < 4; i++) {
            short* d = &Xs[xr[i]][xc[i]];
            d[0] = f2bf(xa[i].x); d[1] = f2bf(xa[i].y);
            d[2] = f2bf(xa[i].z); d[3] = f2bf(xa[i].w);
        }
#pragma unroll
        for (int i = 0; i < 2; i++) {
            short* d = &Gs[wr[i]][wc[i]];
            d[0] = f2bf(ga[i].x); d[1] = f2bf(ga[i].y);
            d[2] = f2bf(ga[i].z); d[3] = f2bf(ga[i].w);
            short* d2 = &Us[wr[i]][wc[i]];
            d2[0] = f2bf(ua[i].x); d2[1] = f2bf(ua[i].y);
            d2[2] = f2bf(ua[i].z); d2[3] = f2bf(ua[i].w);
        }
        __syncthreads();
        if (k0 + 32 < HIDDEN) {
            int kn = k0 + 32;
#pragma unroll
            for (int i = 0; i < 4; i++) xa[i] = *(const float4*)(xp[i] + kn);
#pragma unroll
            for (int i = 0; i < 2; i++) { ga[i] = *(const float4*)(gp[i] + kn); ua[i] = *(const float4*)(up[i] + kn); }
        }
        short8 af[4], bg[2], bu[2];
#pragma unroll
        for (int mi = 0; mi < 4; mi++) af[mi] = *(const short8*)&Xs[wm + mi * 16 + l15][lq * 8];
#pragma unroll
        for (int ni = 0; ni < 2; ni++) {
            bg[ni] = *(const short8*)&Gs[wn + ni * 16 + l15][lq * 8];
            bu[ni] = *(const short8*)&Us[wn + ni * 16 + l15][lq * 8];
        }
#pragma unroll
        for (int mi = 0; mi < 4; mi++)
#pragma unroll
            for (int ni = 0; ni < 2; ni++) {
                cg[mi][ni] = __builtin_amdgcn_mfma_f32_16x16x32_bf16(af[mi], bg[ni], cg[mi][ni], 0, 0, 0);
                cu[mi][ni] = __builtin_amdgcn_mfma_f32_16x16x32_bf16(af[mi], bu[ni], cu[mi][ni], 0, 0, 0);
            }
    }

#pragma unroll
    for (int mi = 0; mi < 4; mi++)
#pragma unroll
        for (int r = 0; r < 4; r++) {
            int row = wm + mi * 16 + lq * 4 + r;
            int grow = row0 + row;
            if (grow < cnt) {
                __hip_bfloat16* hrow = hbuf + (size_t)(off_e + grow) * FFN + f0 + wn;
#pragma unroll
                for (int ni = 0; ni < 2; ni++) {
                    float g = cg[mi][ni][r], u = cu[mi][ni][r];
                    float h = g / (1.f + __expf(-g)) * u;
                    hrow[ni * 16 + l15] = __float2bfloat16(h);
                }
            }
        }
}

__global__ void __launch_bounds__(256, 2)
ffn2_fb(const __hip_bfloat16* __restrict__ hbuf, const float* __restrict__ Wd,
        const int* __restrict__ counts, const int* __restrict__ tok,
        const float* __restrict__ wts, float* __restrict__ out)
{
    int e = blockIdx.z;
    int cnt = counts[e];
    int row0 = blockIdx.x * 128;
    if (row0 >= cnt) return;
    int off_e = 0;
#pragma unroll
    for (int i = 0; i < NEXP; i++) if (i < e) off_e += counts[i];
    int h0 = blockIdx.y * 64;

    __shared__ short Hs[128][LDW];
    __shared__ short Ds[64][LDW];
    __shared__ int   stok[128];
    __shared__ float swt[128];

    int tid = threadIdx.x;
    if (tid < 128) {
        int rc = min(row0 + tid, cnt - 1);
        stok[tid] = tok[e * NTOK + rc];
        swt[tid]  = wts[e * NTOK + rc];
    }
    __syncthreads();

    int lane = tid & 63, w = tid >> 6;
    int wm = (w & 1) * 64, wn = (w >> 1) * 32;
    int l15 = lane & 15, lq = lane >> 4;

    f32x4 c[4][2];
#pragma unroll
    for (int i = 0; i < 4; i++)
#pragma unroll
        for (int j = 0; j < 2; j++) c[i][j] = (f32x4)0.f;

    const float* Wde = Wd + (size_t)e * HIDDEN * FFN;

    int hr[2], hc[2]; const short* hp[2];
#pragma unroll
    for (int i = 0; i < 2; i++) {
        int idx = tid + 256 * i;
        hr[i] = idx >> 2; hc[i] = (idx & 3) * 8;
        int ar = min(row0 + hr[i], cnt - 1);
        hp[i] = (const short*)(hbuf + (size_t)(off_e + ar) * FFN + hc[i]);
    }
    int dr[2], dc[2]; const float* dp[2];
#pragma unroll
    for (int i = 0; i < 2; i++) {
        int idx = tid + 256 * i;
        dr[i] = idx >> 3; dc[i] = (idx & 7) * 4;
        dp[i] = Wde + (size_t)(h0 + dr[i]) * FFN + dc[i];
    }

    short8 ha[2]; float4 da[2];
#pragma unroll
    for (int i = 0; i < 2; i++) { ha[i] = *(const short8*)(hp[i]); da[i] = *(const float4*)(dp[i]); }

    for (int k0 = 0; k0 < FFN; k0 += 32) {
        __syncthreads();
#pragma unroll
        for (int i = 0; i < 2; i++) {
            *(short8*)&Hs[hr[i]][hc[i]] = ha[i];
            short* d = &Ds[dr[i]][dc[i]];
            d[0] = f2bf(da[i].x); d[1] = f2bf(da[i].y);
            d[2] = f2bf(da[i].z); d[3] = f2bf(da[i].w);
        }
        __syncthreads();
        if (k0 + 32 < FFN) {
            int kn = k0 + 32;
#pragma unroll
            for (int i = 0; i < 2; i++) { ha[i] = *(const short8*)(hp[i] + kn); da[i] = *(const float4*)(dp[i] + kn); }
        }
        short8 af[4], bf_[2];
#pragma unroll
        for (int mi = 0; mi < 4; mi++) af[mi] = *(const short8*)&Hs[wm + mi * 16 + l15][lq * 8];
#pragma unroll
        for (int ni = 0; ni < 2; ni++) bf_[ni] = *(const short8*)&Ds[wn + ni * 16 + l15][lq * 8];
#pragma unroll
        for (int mi = 0; mi < 4; mi++)
#pragma unroll
            for (int ni = 0; ni < 2; ni++)
                c[mi][ni] = __builtin_amdgcn_mfma_f32_16x16x32_bf16(af[mi], bf_[ni], c[mi][ni], 0, 0, 0);
    }

#pragma unroll
    for (int mi = 0; mi < 4; mi++)
#pragma unroll
        for (int r = 0; r < 4; r++) {
            int row = wm + mi * 16 + lq * 4 + r;
            int grow = row0 + row;
            if (grow < cnt) {
                int t = stok[row];
                float wgt = swt[row];
                float* orow = out + (size_t)t * HIDDEN + h0 + wn;
#pragma unroll
                for (int ni = 0; ni < 2; ni++)
                    atomicAdd(&orow[ni * 16 + l15], wgt * c[mi][ni][r]);
            }
        }
}

extern "C" void kernel_launch(void* const* d_in, const int* in_sizes, int n_in,
                              void* d_out, int out_size, void* d_ws, size_t ws_size,
                              hipStream_t stream) {
    const float* x     = (const float*)d_in[0];
    const float* Wgate = (const float*)d_in[1];
    const float* Wg    = (const float*)d_in[2];
    const float* Wu    = (const float*)d_in[3];
    const float* Wd    = (const float*)d_in[4];
    float* out = (float*)d_out;

    char* ws = (char*)d_ws;
    int*   counts = (int*)ws;
    int*   tok    = (int*)(ws + 256);
    float* wts    = (float*)(ws + 256 + NEXP * NTOK * 4);

    hipMemsetAsync(counts, 0, 256, stream);

    const size_t base = 256 + 2 * (size_t)NEXP * NTOK * 4;   // 131328
    const size_t NEED = base
        + 2ull * NTOK * HIDDEN                // xbf
        + 2ull * 2ull * NTOK * FFN;           // hbuf (4096 x 2816)

    if (ws_size >= NEED) {
        short* xbf  = (short*)(ws + base);
        short* hbuf = xbf + (size_t)NTOK * HIDDEN;

        // launch 1: router + x->bf16 + out zero-fill (1536 blocks)
        fused_rxz<<<1536, 256, 0, stream>>>(x, Wgate, counts, tok, wts, xbf, out);

        // launch 2: ffn1, fp32 weights direct (v7 structure, no cvt tail)
        ffn1_v10<<<FFN1_BLOCKS, 256, 0, stream>>>(xbf, Wg, Wu, counts, tok, hbuf);

        // launch 3: ffn2, fp32 Wd direct (reg-staged) -- wdbf eliminated
        ffn2_v9<<<2048, 256, 0, stream>>>(hbuf, Wd, counts, tok, wts, out);
    } else {
        hipMemsetAsync(out, 0, (size_t)out_size * sizeof(float), stream);
        router_kernel<<<NTOK, 64, 0, stream>>>(x, Wgate, counts, tok, wts);
        __hip_bfloat16* hbuf = (__hip_bfloat16*)(ws + base);
        dim3 g1(NTOK / 128, FFN / 64, NEXP);
        ffn1_fb<<<g1, 256, 0, stream>>>(x, Wg, Wu, counts, tok, hbuf);
        dim3 g2(NTOK / 128, HIDDEN / 64, NEXP);
        ffn2_fb<<<g2, 256, 0, stream>>>(hbuf, Wd, counts, tok, wts, out);
    }
}